// Round 3
// baseline (4792.236 us; speedup 1.0000x reference)
//
#include <hip/hip_runtime.h>

static constexpr int B = 8;
static constexpr int C = 32;
static constexpr int RES_[3]  = {64, 128, 256};
static constexpr int NPTS_[3] = {65536, 32768, 16384};

// ---------------------------------------------------------------------------
// Scatter: 8 threads per point. Each thread handles 4 channels (float4 load,
// coalesced). Index chain in f32 matching the XLA-simplified pipeline:
//   u = x * (1/denom) + 0.5   (recip constant-folded in f32, NO fma)
//   u = clamp(u, 0, 1-1e-5);  idx = trunc(u * res)
// 12 feature atomics + (lane q==0) 3 count atomics per point.
// Grid: x = N*8/256 blocks, y = B.
// ---------------------------------------------------------------------------
__global__ __launch_bounds__(256) void scatter_kernel(
    const float* __restrict__ feats,   // (B,N,32)
    const float* __restrict__ coords,  // (B,N,3)
    float* __restrict__ out,           // scale base: 3 planes x (B,32,R2), zeroed
    unsigned int* __restrict__ cnt,    // scale base: 3 planes x (B,R2), zeroed
    int N, int res)
{
#pragma clang fp contract(off)
    const int b = blockIdx.y;
    const int p = blockIdx.x * 32 + (threadIdx.x >> 3);  // point within batch
    const int q = threadIdx.x & 7;                        // channel quad
    const size_t pt = (size_t)b * N + p;

    const float* cc = coords + pt * 3;
    const float x = cc[0], y = cc[1], z = cc[2];

    // XLA algsimp: divide(x, c) -> multiply(x, 1/c), reciprocal folded in f32.
    constexpr float denomf = (float)(1.0 + 0.1 + 1e-5);   // 1.10001f
    constexpr float recipf = 1.0f / denomf;               // f32 correctly-rounded
    constexpr float hi     = (float)(1.0 - 1e-5);         // 0.99999f
    const float rf = (float)res;

    const float tx = x * recipf;  // separate mul/add: no fma (contract off)
    const float ty = y * recipf;
    const float tz = z * recipf;
    const float ux = fminf(fmaxf(tx + 0.5f, 0.0f), hi);
    const float uy = fminf(fmaxf(ty + 0.5f, 0.0f), hi);
    const float uz = fminf(fmaxf(tz + 0.5f, 0.0f), hi);
    const int ix = (int)(ux * rf);
    const int iy = (int)(uy * rf);
    const int iz = (int)(uz * rf);

    const int R2 = res * res;
    int idxs[3];
    idxs[0] = ix + res * iz;   // "xz"
    idxs[1] = ix + res * iy;   // "xy"
    idxs[2] = iy + res * iz;   // "yz"

    const float4 f = *(const float4*)(feats + pt * C + q * 4);

    const size_t planeStride = (size_t)B * C * R2;
    const size_t chBase = ((size_t)b * C + q * 4) * (size_t)R2;

#pragma unroll
    for (int k = 0; k < 3; ++k) {
        float* o = out + (size_t)k * planeStride + chBase + idxs[k];
        atomicAdd(o,                  f.x);
        atomicAdd(o + (size_t)R2,     f.y);
        atomicAdd(o + (size_t)2 * R2, f.z);
        atomicAdd(o + (size_t)3 * R2, f.w);
    }
    if (q == 0) {
#pragma unroll
        for (int k = 0; k < 3; ++k) {
            atomicAdd(cnt + (size_t)k * B * R2 + (size_t)b * R2 + idxs[k], 1u);
        }
    }
}

// ---------------------------------------------------------------------------
// Finalize: out[e] /= max(count,1). float4 per thread.
// Grid: x = R2/1024 blocks (256 thr * 4 cells), y = 3*B*C (= plane*B*C+b*C+ch)
// ---------------------------------------------------------------------------
__global__ __launch_bounds__(256) void finalize_kernel(
    float* __restrict__ out, const unsigned int* __restrict__ cnt, int R2)
{
    const int cq = blockIdx.x * 256 + threadIdx.x;  // cell quad index
    const int t  = blockIdx.y;                      // plane*B*C + b*C + ch
    const int pb = t >> 5;                          // plane*B + b   (C==32)

    const uint4 cv = *(const uint4*)(cnt + (size_t)pb * R2 + (size_t)cq * 4);
    float4 v = *(const float4*)(out + (size_t)t * R2 + (size_t)cq * 4);
    v.x = v.x / fmaxf((float)cv.x, 1.0f);
    v.y = v.y / fmaxf((float)cv.y, 1.0f);
    v.z = v.z / fmaxf((float)cv.z, 1.0f);
    v.w = v.w / fmaxf((float)cv.w, 1.0f);
    *(float4*)(out + (size_t)t * R2 + (size_t)cq * 4) = v;
}

extern "C" void kernel_launch(void* const* d_in, const int* in_sizes, int n_in,
                              void* d_out, int out_size, void* d_ws, size_t ws_size,
                              hipStream_t stream)
{
    // setup_inputs() dict order is interleaved: f0,c0,f1,c1,f2,c2.
    // Detect defensively via sizes (f1 > f2 > all coords).
    const float *f[3], *c[3];
    const bool interleaved = in_sizes[1] < in_sizes[2];
    if (interleaved) {
        f[0] = (const float*)d_in[0]; c[0] = (const float*)d_in[1];
        f[1] = (const float*)d_in[2]; c[1] = (const float*)d_in[3];
        f[2] = (const float*)d_in[4]; c[2] = (const float*)d_in[5];
    } else {
        f[0] = (const float*)d_in[0]; f[1] = (const float*)d_in[1];
        f[2] = (const float*)d_in[2];
        c[0] = (const float*)d_in[3]; c[1] = (const float*)d_in[4];
        c[2] = (const float*)d_in[5];
    }

    float* out = (float*)d_out;
    unsigned int* cnt = (unsigned int*)d_ws;

    size_t outOff[3], cntOff[3];
    size_t oo = 0, co = 0;
    for (int s = 0; s < 3; ++s) {
        outOff[s] = oo; cntOff[s] = co;
        const size_t R2 = (size_t)RES_[s] * RES_[s];
        oo += (size_t)3 * B * C * R2;   // 3 planes of (B,C,R2) sums (in d_out)
        co += (size_t)3 * B * R2;       // 3 planes of (B,R2) counts (in d_ws)
    }

    // Zero accumulators (harness poisons d_out/d_ws with 0xAA every call).
    hipMemsetAsync(d_out, 0, oo * sizeof(float), stream);
    hipMemsetAsync(d_ws, 0, co * sizeof(unsigned int), stream);

    for (int s = 0; s < 3; ++s) {
        const int N = NPTS_[s], res = RES_[s];
        dim3 grid(N * 8 / 256, B);
        scatter_kernel<<<grid, 256, 0, stream>>>(f[s], c[s], out + outOff[s],
                                                 cnt + cntOff[s], N, res);
    }
    for (int s = 0; s < 3; ++s) {
        const int res = RES_[s], R2 = res * res;
        dim3 grid(R2 / 1024, 3 * B * C);
        finalize_kernel<<<grid, 256, 0, stream>>>(out + outOff[s],
                                                  cnt + cntOff[s], R2);
    }
}

// Round 4
// 1043.474 us; speedup vs baseline: 4.5926x; 4.5926x over previous
//
#include <hip/hip_runtime.h>

static constexpr int B = 8;
static constexpr int C = 32;
static constexpr int RES_[3]  = {64, 128, 256};
static constexpr int NPTS_[3] = {65536, 32768, 16384};

// ---------------------------------------------------------------------------
// Index chain (must stay bit-identical to the XLA pipeline verified in R3):
// u = x * (1/1.10001f) + 0.5f (separate mul/add, NO fma), clamp [0, 0.99999f],
// trunc(u * res).
// ---------------------------------------------------------------------------
__device__ __forceinline__ void plane_cells(float x, float y, float z, int res,
                                            int idxs[3])
{
#pragma clang fp contract(off)
    constexpr float denomf = (float)(1.0 + 0.1 + 1e-5);
    constexpr float recipf = 1.0f / denomf;
    constexpr float hi     = (float)(1.0 - 1e-5);
    const float rf = (float)res;
    const float tx = x * recipf;
    const float ty = y * recipf;
    const float tz = z * recipf;
    const float ux = fminf(fmaxf(tx + 0.5f, 0.0f), hi);
    const float uy = fminf(fmaxf(ty + 0.5f, 0.0f), hi);
    const float uz = fminf(fmaxf(tz + 0.5f, 0.0f), hi);
    const int ix = (int)(ux * rf);
    const int iy = (int)(uy * rf);
    const int iz = (int)(uz * rf);
    idxs[0] = ix + res * iz;   // "xz"
    idxs[1] = ix + res * iy;   // "xy"
    idxs[2] = iy + res * iz;   // "yz"
}

// ---------------------------------------------------------------------------
// K1: per point, per plane: rank = atomicAdd(count[cell]) (only 3 atomics per
// point vs 96 before), store record (cell<<16 | rank). cell<=65535, rank<=65535.
// Grid: (N/256, B).
// ---------------------------------------------------------------------------
__global__ __launch_bounds__(256) void count_rank_kernel(
    const float* __restrict__ coords,   // (B,N,3)
    unsigned int* __restrict__ cnt,     // (3,B,R2) zeroed
    unsigned int* __restrict__ rec,     // (3,B,N)
    int N, int res)
{
    const int b = blockIdx.y;
    const int p = blockIdx.x * 256 + threadIdx.x;
    const size_t pt = (size_t)b * N + p;
    const float x = coords[pt * 3 + 0];
    const float y = coords[pt * 3 + 1];
    const float z = coords[pt * 3 + 2];
    int idxs[3];
    plane_cells(x, y, z, res, idxs);
    const int R2 = res * res;
#pragma unroll
    for (int k = 0; k < 3; ++k) {
        const unsigned int cell = (unsigned int)idxs[k];
        const unsigned int rank =
            atomicAdd(&cnt[((size_t)k * B + b) * R2 + cell], 1u);
        rec[((size_t)k * B + b) * N + p] = (cell << 16) | rank;
    }
}

// ---------------------------------------------------------------------------
// K2: exclusive prefix sum over each (plane,b) segment of R2 counts.
// One block (1024 thr) per segment; thread owns R2/1024 consecutive elems.
// ---------------------------------------------------------------------------
__global__ __launch_bounds__(1024) void scan_kernel(
    const unsigned int* __restrict__ cnt, unsigned int* __restrict__ off, int R2)
{
    __shared__ unsigned int sdata[1024];
    const int seg = blockIdx.x;                 // k*B + b
    const size_t base = (size_t)seg * R2;
    const int E = R2 / 1024;
    const int tid = threadIdx.x;
    unsigned int tsum = 0;
    for (int i = 0; i < E; ++i) tsum += cnt[base + (size_t)tid * E + i];
    sdata[tid] = tsum;
    __syncthreads();
    for (int d = 1; d < 1024; d <<= 1) {
        unsigned int v = (tid >= d) ? sdata[tid - d] : 0u;
        __syncthreads();
        sdata[tid] += v;
        __syncthreads();
    }
    unsigned int run = sdata[tid] - tsum;       // exclusive prefix of tsums
    for (int i = 0; i < E; ++i) {
        const unsigned int c = cnt[base + (size_t)tid * E + i];
        off[base + (size_t)tid * E + i] = run;
        run += c;
    }
}

// ---------------------------------------------------------------------------
// K3: invert: list[offset[cell] + rank] = point id. No atomics (ranks unique).
// Grid: (N/256, 3*B).
// ---------------------------------------------------------------------------
__global__ __launch_bounds__(256) void build_list_kernel(
    const unsigned int* __restrict__ rec, const unsigned int* __restrict__ off,
    unsigned short* __restrict__ list, int N, int R2)
{
    const int kb = blockIdx.y;
    const int p = blockIdx.x * 256 + threadIdx.x;
    const unsigned int r = rec[(size_t)kb * N + p];
    const unsigned int cell = r >> 16;
    const unsigned int rank = r & 0xffffu;
    const unsigned int pos = off[(size_t)kb * R2 + cell] + rank;
    list[(size_t)kb * N + pos] = (unsigned short)p;
}

// ---------------------------------------------------------------------------
// K4: gather + mean + write. Half-wave (32 lanes = 32 channels) per cell;
// each point's feature row is one coalesced 128B load. 16 cells per half-wave
// accumulated in registers, LDS transpose, coalesced final writes (also writes
// zeros for empty cells -> no d_out memset, no finalize kernel).
// Grid: (R2/128, 3*B).
// ---------------------------------------------------------------------------
__global__ __launch_bounds__(256) void gather_mean_kernel(
    const float* __restrict__ feats,            // (B,N,32)
    const unsigned int* __restrict__ cnt,
    const unsigned int* __restrict__ off,
    const unsigned short* __restrict__ list,
    float* __restrict__ out,                    // scale base (3,B,C,R2)
    int N, int R2)
{
    __shared__ float tile[C][128 + 1];
    const int kb = blockIdx.y;                  // k*B + b
    const int b  = kb & (B - 1);
    const int cellBase = blockIdx.x * 128;
    const int h  = threadIdx.x >> 5;            // half-wave id (0..7)
    const int ch = threadIdx.x & 31;            // channel
    const size_t segBase  = (size_t)kb * R2;
    const size_t listBase = (size_t)kb * N;

#pragma unroll 1
    for (int i = 0; i < 16; ++i) {
        const int cell = cellBase + h * 16 + i;
        const unsigned int n = cnt[segBase + cell];
        const unsigned int o = off[segBase + cell];
        float a = 0.0f;
        for (unsigned int j = 0; j < n; ++j) {
            const int ptp = list[listBase + o + j];
            a += feats[((size_t)b * N + ptp) * C + ch];
        }
        a /= fmaxf((float)n, 1.0f);
        tile[ch][h * 16 + i] = a;               // stride-129 -> conflict-free
    }
    __syncthreads();
#pragma unroll
    for (int c2 = 0; c2 < C; c2 += 2) {
        const int ch2  = c2 + (threadIdx.x >> 7);
        const int cell = threadIdx.x & 127;
        out[((size_t)kb * C + ch2) * R2 + cellBase + cell] = tile[ch2][cell];
    }
}

extern "C" void kernel_launch(void* const* d_in, const int* in_sizes, int n_in,
                              void* d_out, int out_size, void* d_ws, size_t ws_size,
                              hipStream_t stream)
{
    const float *f[3], *c[3];
    const bool interleaved = in_sizes[1] < in_sizes[2];
    if (interleaved) {
        f[0] = (const float*)d_in[0]; c[0] = (const float*)d_in[1];
        f[1] = (const float*)d_in[2]; c[1] = (const float*)d_in[3];
        f[2] = (const float*)d_in[4]; c[2] = (const float*)d_in[5];
    } else {
        f[0] = (const float*)d_in[0]; f[1] = (const float*)d_in[1];
        f[2] = (const float*)d_in[2];
        c[0] = (const float*)d_in[3]; c[1] = (const float*)d_in[4];
        c[2] = (const float*)d_in[5];
    }

    float* out = (float*)d_out;

    // ---- workspace layout (u32 units): cnt[3] | off[3] | rec[3] | list(u16)
    size_t cntOff[3], offOff[3], recOff[3], listOff[3];  // listOff in u16 units
    size_t u = 0;
    for (int s = 0; s < 3; ++s) {
        cntOff[s] = u; u += (size_t)3 * B * RES_[s] * RES_[s];
    }
    const size_t cntTotal = u;
    for (int s = 0; s < 3; ++s) {
        offOff[s] = u; u += (size_t)3 * B * RES_[s] * RES_[s];
    }
    for (int s = 0; s < 3; ++s) {
        recOff[s] = u; u += (size_t)3 * B * NPTS_[s];
    }
    size_t u16base = u * 2;  // in u16 units
    for (int s = 0; s < 3; ++s) {
        listOff[s] = u16base; u16base += (size_t)3 * B * NPTS_[s];
    }

    unsigned int* ws32 = (unsigned int*)d_ws;
    unsigned short* ws16 = (unsigned short*)d_ws;

    // output offsets per scale (3 planes x (B,C,R2) each)
    size_t outOff[3]; size_t oo = 0;
    for (int s = 0; s < 3; ++s) {
        outOff[s] = oo;
        oo += (size_t)3 * B * C * RES_[s] * RES_[s];
    }

    // zero only the count grids (8.3 MB)
    hipMemsetAsync(d_ws, 0, cntTotal * sizeof(unsigned int), stream);

    for (int s = 0; s < 3; ++s) {
        const int N = NPTS_[s], res = RES_[s];
        dim3 grid(N / 256, B);
        count_rank_kernel<<<grid, 256, 0, stream>>>(
            c[s], ws32 + cntOff[s], ws32 + recOff[s], N, res);
    }
    for (int s = 0; s < 3; ++s) {
        const int R2 = RES_[s] * RES_[s];
        scan_kernel<<<3 * B, 1024, 0, stream>>>(
            ws32 + cntOff[s], ws32 + offOff[s], R2);
    }
    for (int s = 0; s < 3; ++s) {
        const int N = NPTS_[s], R2 = RES_[s] * RES_[s];
        dim3 grid(N / 256, 3 * B);
        build_list_kernel<<<grid, 256, 0, stream>>>(
            ws32 + recOff[s], ws32 + offOff[s], ws16 + listOff[s], N, R2);
    }
    for (int s = 0; s < 3; ++s) {
        const int N = NPTS_[s], R2 = RES_[s] * RES_[s];
        dim3 grid(R2 / 128, 3 * B);
        gather_mean_kernel<<<grid, 256, 0, stream>>>(
            f[s], ws32 + cntOff[s], ws32 + offOff[s], ws16 + listOff[s],
            out + outOff[s], N, R2);
    }
}

// Round 5
// 775.213 us; speedup vs baseline: 6.1818x; 1.3460x over previous
//
#include <hip/hip_runtime.h>

static constexpr int B = 8;
static constexpr int C = 32;
static constexpr int RES_[3]  = {64, 128, 256};
static constexpr int NPTS_[3] = {65536, 32768, 16384};

// ---------------------------------------------------------------------------
// Index chain (bit-identical to the XLA pipeline verified in R3):
// u = x * (1/1.10001f) + 0.5f (separate mul/add, NO fma), clamp [0, 0.99999f],
// trunc(u * res).
// ---------------------------------------------------------------------------
__device__ __forceinline__ void plane_cells(float x, float y, float z, int res,
                                            int idxs[3])
{
#pragma clang fp contract(off)
    constexpr float denomf = (float)(1.0 + 0.1 + 1e-5);
    constexpr float recipf = 1.0f / denomf;
    constexpr float hi     = (float)(1.0 - 1e-5);
    const float rf = (float)res;
    const float tx = x * recipf;
    const float ty = y * recipf;
    const float tz = z * recipf;
    const float ux = fminf(fmaxf(tx + 0.5f, 0.0f), hi);
    const float uy = fminf(fmaxf(ty + 0.5f, 0.0f), hi);
    const float uz = fminf(fmaxf(tz + 0.5f, 0.0f), hi);
    const int ix = (int)(ux * rf);
    const int iy = (int)(uy * rf);
    const int iz = (int)(uz * rf);
    idxs[0] = ix + res * iz;   // "xz"
    idxs[1] = ix + res * iy;   // "xy"
    idxs[2] = iy + res * iz;   // "yz"
}

// ---------------------------------------------------------------------------
// K1: per point, per plane: rank = atomicAdd(count[cell]), store (cell<<16|rank).
// ---------------------------------------------------------------------------
__global__ __launch_bounds__(256) void count_rank_kernel(
    const float* __restrict__ coords,   // (B,N,3)
    unsigned int* __restrict__ cnt,     // (3,B,R2) zeroed
    unsigned int* __restrict__ rec,     // (3,B,N)
    int N, int res)
{
    const int b = blockIdx.y;
    const int p = blockIdx.x * 256 + threadIdx.x;
    const size_t pt = (size_t)b * N + p;
    const float x = coords[pt * 3 + 0];
    const float y = coords[pt * 3 + 1];
    const float z = coords[pt * 3 + 2];
    int idxs[3];
    plane_cells(x, y, z, res, idxs);
    const int R2 = res * res;
#pragma unroll
    for (int k = 0; k < 3; ++k) {
        const unsigned int cell = (unsigned int)idxs[k];
        const unsigned int rank =
            atomicAdd(&cnt[((size_t)k * B + b) * R2 + cell], 1u);
        rec[((size_t)k * B + b) * N + p] = (cell << 16) | rank;
    }
}

// ---------------------------------------------------------------------------
// K2: exclusive prefix sum over each (plane,b) segment of R2 counts.
// ---------------------------------------------------------------------------
__global__ __launch_bounds__(1024) void scan_kernel(
    const unsigned int* __restrict__ cnt, unsigned int* __restrict__ off, int R2)
{
    __shared__ unsigned int sdata[1024];
    const int seg = blockIdx.x;                 // k*B + b
    const size_t base = (size_t)seg * R2;
    const int E = R2 / 1024;
    const int tid = threadIdx.x;
    unsigned int tsum = 0;
    for (int i = 0; i < E; ++i) tsum += cnt[base + (size_t)tid * E + i];
    sdata[tid] = tsum;
    __syncthreads();
    for (int d = 1; d < 1024; d <<= 1) {
        unsigned int v = (tid >= d) ? sdata[tid - d] : 0u;
        __syncthreads();
        sdata[tid] += v;
        __syncthreads();
    }
    unsigned int run = sdata[tid] - tsum;       // exclusive prefix of tsums
    for (int i = 0; i < E; ++i) {
        const unsigned int c = cnt[base + (size_t)tid * E + i];
        off[base + (size_t)tid * E + i] = run;
        run += c;
    }
}

// ---------------------------------------------------------------------------
// K3: invert: list[offset[cell] + rank] = point id. No atomics.
// ---------------------------------------------------------------------------
__global__ __launch_bounds__(256) void build_list_kernel(
    const unsigned int* __restrict__ rec, const unsigned int* __restrict__ off,
    unsigned short* __restrict__ list, int N, int R2)
{
    const int kb = blockIdx.y;
    const int p = blockIdx.x * 256 + threadIdx.x;
    const unsigned int r = rec[(size_t)kb * N + p];
    const unsigned int cell = r >> 16;
    const unsigned int rank = r & 0xffffu;
    const unsigned int pos = off[(size_t)kb * R2 + cell] + rank;
    list[(size_t)kb * N + pos] = (unsigned short)p;
}

// ---------------------------------------------------------------------------
// K4: gather + mean + write. 64 cells/block (half-wave of 32 lanes = channels,
// 8 cells each). cnt/off LDS-staged (kills the 2-dependent-load-per-cell
// chain). Point loop unrolled x4: 4 list loads + 4 independent feats gathers
// in flight (MLP). LDS transpose -> coalesced writes (zeros for empty cells).
// Grid: (R2/64, 3*B).
// ---------------------------------------------------------------------------
__global__ __launch_bounds__(256) void gather_mean_kernel(
    const float* __restrict__ feats,            // (B,N,32)
    const unsigned int* __restrict__ cnt,
    const unsigned int* __restrict__ off,
    const unsigned short* __restrict__ list,
    float* __restrict__ out,                    // scale base (3,B,C,R2)
    int N, int R2)
{
    __shared__ float tile[C][64 + 1];
    __shared__ unsigned int s_cnt[64];
    __shared__ unsigned int s_off[64];
    const int kb = blockIdx.y;                  // k*B + b
    const int b  = kb & (B - 1);
    const int cellBase = blockIdx.x * 64;
    const int h  = threadIdx.x >> 5;            // 32-lane group id (0..7)
    const int ch = threadIdx.x & 31;            // channel
    const size_t segBase  = (size_t)kb * R2;
    const size_t listBase = (size_t)kb * N;
    const float* frow = feats + (size_t)b * N * C + ch;

    if (threadIdx.x < 64) {
        s_cnt[threadIdx.x] = cnt[segBase + cellBase + threadIdx.x];
        s_off[threadIdx.x] = off[segBase + cellBase + threadIdx.x];
    }
    __syncthreads();

    for (int i = 0; i < 8; ++i) {
        const int lc = h * 8 + i;
        const unsigned int n = s_cnt[lc];
        const unsigned int o = s_off[lc];
        const unsigned short* lp = list + listBase + o;
        float a = 0.0f;
        unsigned int j = 0;
        for (; j + 4 <= n; j += 4) {
            const int p0 = lp[j + 0];
            const int p1 = lp[j + 1];
            const int p2 = lp[j + 2];
            const int p3 = lp[j + 3];
            const float v0 = frow[(size_t)p0 * C];
            const float v1 = frow[(size_t)p1 * C];
            const float v2 = frow[(size_t)p2 * C];
            const float v3 = frow[(size_t)p3 * C];
            a += (v0 + v1) + (v2 + v3);
        }
        for (; j < n; ++j) a += frow[(size_t)lp[j] * C];
        a /= fmaxf((float)n, 1.0f);
        tile[ch][lc] = a;                       // stride-65: conflict-free
    }
    __syncthreads();
#pragma unroll
    for (int c8 = 0; c8 < 8; ++c8) {
        const int ch2  = c8 * 4 + (threadIdx.x >> 6);
        const int cell = threadIdx.x & 63;
        out[((size_t)kb * C + ch2) * R2 + cellBase + cell] = tile[ch2][cell];
    }
}

extern "C" void kernel_launch(void* const* d_in, const int* in_sizes, int n_in,
                              void* d_out, int out_size, void* d_ws, size_t ws_size,
                              hipStream_t stream)
{
    const float *f[3], *c[3];
    const bool interleaved = in_sizes[1] < in_sizes[2];
    if (interleaved) {
        f[0] = (const float*)d_in[0]; c[0] = (const float*)d_in[1];
        f[1] = (const float*)d_in[2]; c[1] = (const float*)d_in[3];
        f[2] = (const float*)d_in[4]; c[2] = (const float*)d_in[5];
    } else {
        f[0] = (const float*)d_in[0]; f[1] = (const float*)d_in[1];
        f[2] = (const float*)d_in[2];
        c[0] = (const float*)d_in[3]; c[1] = (const float*)d_in[4];
        c[2] = (const float*)d_in[5];
    }

    float* out = (float*)d_out;

    // ---- workspace layout (u32 units): cnt[3] | off[3] | rec[3] | list(u16)
    size_t cntOff[3], offOff[3], recOff[3], listOff[3];  // listOff in u16 units
    size_t u = 0;
    for (int s = 0; s < 3; ++s) {
        cntOff[s] = u; u += (size_t)3 * B * RES_[s] * RES_[s];
    }
    const size_t cntTotal = u;
    for (int s = 0; s < 3; ++s) {
        offOff[s] = u; u += (size_t)3 * B * RES_[s] * RES_[s];
    }
    for (int s = 0; s < 3; ++s) {
        recOff[s] = u; u += (size_t)3 * B * NPTS_[s];
    }
    size_t u16base = u * 2;  // in u16 units
    for (int s = 0; s < 3; ++s) {
        listOff[s] = u16base; u16base += (size_t)3 * B * NPTS_[s];
    }

    unsigned int* ws32 = (unsigned int*)d_ws;
    unsigned short* ws16 = (unsigned short*)d_ws;

    // output offsets per scale (3 planes x (B,C,R2) each)
    size_t outOff[3]; size_t oo = 0;
    for (int s = 0; s < 3; ++s) {
        outOff[s] = oo;
        oo += (size_t)3 * B * C * RES_[s] * RES_[s];
    }

    // zero only the count grids (8.3 MB)
    hipMemsetAsync(d_ws, 0, cntTotal * sizeof(unsigned int), stream);

    for (int s = 0; s < 3; ++s) {
        const int N = NPTS_[s], res = RES_[s];
        dim3 grid(N / 256, B);
        count_rank_kernel<<<grid, 256, 0, stream>>>(
            c[s], ws32 + cntOff[s], ws32 + recOff[s], N, res);
    }
    for (int s = 0; s < 3; ++s) {
        const int R2 = RES_[s] * RES_[s];
        scan_kernel<<<3 * B, 1024, 0, stream>>>(
            ws32 + cntOff[s], ws32 + offOff[s], R2);
    }
    for (int s = 0; s < 3; ++s) {
        const int N = NPTS_[s], R2 = RES_[s] * RES_[s];
        dim3 grid(N / 256, 3 * B);
        build_list_kernel<<<grid, 256, 0, stream>>>(
            ws32 + recOff[s], ws32 + offOff[s], ws16 + listOff[s], N, R2);
    }
    for (int s = 0; s < 3; ++s) {
        const int N = NPTS_[s], R2 = RES_[s] * RES_[s];
        dim3 grid(R2 / 64, 3 * B);
        gather_mean_kernel<<<grid, 256, 0, stream>>>(
            f[s], ws32 + cntOff[s], ws32 + offOff[s], ws16 + listOff[s],
            out + outOff[s], N, R2);
    }
}